// Round 1
// baseline (4336.892 us; speedup 1.0000x reference)
//
#include <hip/hip_runtime.h>
#include <hip/hip_bf16.h>

// Problem constants (from reference)
#define N_NODES 50000
#define N_EDGES 400000
#define FDIM    256     // F = 2*H1 = 2*H2 = 256 everywhere
#define PPAIRS  100000

typedef float f4 __attribute__((ext_vector_type(4)));
typedef float f2 __attribute__((ext_vector_type(2)));

// ---------------------------------------------------------------------------
// CSR construction (deterministic-enough; only int atomics)
// ---------------------------------------------------------------------------
__global__ void count_deg(const int* __restrict__ dst, int* __restrict__ deg, int e) {
    int t = blockIdx.x * blockDim.x + threadIdx.x;
    if (t < e) atomicAdd(&deg[dst[t]], 1);
}

__global__ void exclusive_scan(const int* __restrict__ deg, int* __restrict__ rowptr, int n) {
    __shared__ int sums[1024];
    int t = threadIdx.x;
    int chunk = (n + 1023) >> 10;
    int begin = t * chunk;
    int end   = min(begin + chunk, n);
    int s = 0;
    for (int i = begin; i < end; ++i) s += deg[i];
    sums[t] = s;
    __syncthreads();
    for (int off = 1; off < 1024; off <<= 1) {
        int v = (t >= off) ? sums[t - off] : 0;
        __syncthreads();
        sums[t] += v;
        __syncthreads();
    }
    int prefix = (t == 0) ? 0 : sums[t - 1];
    for (int i = begin; i < end; ++i) { rowptr[i] = prefix; prefix += deg[i]; }
    if (t == 1023) rowptr[n] = sums[1023];
}

__global__ void fill_csr(const int* __restrict__ src, const int* __restrict__ dst,
                         const int* __restrict__ rowptr, int* __restrict__ cursor,
                         int* __restrict__ col, int e) {
    int t = blockIdx.x * blockDim.x + threadIdx.x;
    if (t < e) {
        int d = dst[t];
        int pos = atomicAdd(&cursor[d], 1);
        col[rowptr[d] + pos] = src[t];
    }
}

// ---------------------------------------------------------------------------
// GIN aggregation: h[n,:] = (1+eps)*x[n,:] + sum_{s in in(n)} x[s,:]
// one wave (64 lanes) per node, float4 per lane -> full 256-wide row
// ---------------------------------------------------------------------------
__global__ __launch_bounds__(256) void agg_h(
        const float* __restrict__ x, const int* __restrict__ rowptr,
        const int* __restrict__ col, const float* __restrict__ eps,
        float* __restrict__ h, int n) {
    int gw = (blockIdx.x * 256 + threadIdx.x) >> 6;
    int l  = threadIdx.x & 63;
    if (gw >= n) return;
    float e = 1.0f + eps[0];
    f4 acc = {0.f, 0.f, 0.f, 0.f};
    int b0 = rowptr[gw], b1 = rowptr[gw + 1];
    for (int i = b0; i < b1; ++i) {
        int s = col[i];
        f4 v = *(const f4*)&x[(size_t)s * FDIM + 4 * l];
        acc += v;
    }
    f4 self = *(const f4*)&x[(size_t)gw * FDIM + 4 * l];
    f4 r = e * self + acc;
    *(f4*)&h[(size_t)gw * FDIM + 4 * l] = r;
}

// ---------------------------------------------------------------------------
// fp32 GEMM: C[r, coloff + c] = (relu?)(A[r,:256] @ W[:256, NCOLS] + bias)
// block = 32 rows x NCOLS cols, 256 threads (4 waves; wave w owns rows w+4j)
// lane l owns cols [CPT*l, CPT*l+CPT)
// ---------------------------------------------------------------------------
template <int NCOLS, bool RELU>
__global__ __launch_bounds__(256) void gin_gemm(
        const float* __restrict__ A, const float* __restrict__ W,
        const float* __restrict__ bias, float* __restrict__ C,
        int n, int ldc, int coloff) {
    constexpr int CPT = NCOLS / 64;  // 4 (NCOLS=256) or 2 (NCOLS=128)
    __shared__ __align__(16) float Bt[16][NCOLS];
    __shared__ __align__(16) float At[32][16];
    int t = threadIdx.x;
    int w = t >> 6, l = t & 63;
    int row0 = blockIdx.x * 32;

    float acc[8][CPT];
#pragma unroll
    for (int j = 0; j < 8; ++j)
#pragma unroll
        for (int c = 0; c < CPT; ++c) acc[j][c] = 0.f;

    for (int kb = 0; kb < 256; kb += 16) {
        __syncthreads();
        // B tile: 16 consecutive K-rows of W == contiguous memcpy
        {
            const f4* src = (const f4*)(W + (size_t)kb * NCOLS);
            f4* dstp = (f4*)&Bt[0][0];
#pragma unroll
            for (int q = t; q < 16 * NCOLS / 4; q += 256) dstp[q] = src[q];
        }
        // A tile: 32 rows x 16 K, float2 per thread
        {
            int q = t * 2;
            int r = q >> 4, kk = q & 15;
            int gr = row0 + r;
            if (gr >= n) gr = n - 1;
            *(f2*)&At[r][kk] = *(const f2*)&A[(size_t)gr * 256 + kb + kk];
        }
        __syncthreads();
#pragma unroll
        for (int kk4 = 0; kk4 < 16; kk4 += 4) {
            f4 a4[8];
#pragma unroll
            for (int j = 0; j < 8; ++j) a4[j] = *(f4*)&At[w + 4 * j][kk4];
#pragma unroll
            for (int u = 0; u < 4; ++u) {
                if constexpr (CPT == 4) {
                    f4 b4 = *(f4*)&Bt[kk4 + u][4 * l];
#pragma unroll
                    for (int j = 0; j < 8; ++j) {
                        float a = a4[j][u];
                        acc[j][0] += a * b4[0]; acc[j][1] += a * b4[1];
                        acc[j][2] += a * b4[2]; acc[j][3] += a * b4[3];
                    }
                } else {
                    f2 b2 = *(f2*)&Bt[kk4 + u][2 * l];
#pragma unroll
                    for (int j = 0; j < 8; ++j) {
                        float a = a4[j][u];
                        acc[j][0] += a * b2[0]; acc[j][1] += a * b2[1];
                    }
                }
            }
        }
    }

    // epilogue
    if constexpr (CPT == 4) {
        f4 bv = *(const f4*)&bias[4 * l];
#pragma unroll
        for (int j = 0; j < 8; ++j) {
            int r = row0 + w + 4 * j;
            if (r < n) {
                f4 o;
#pragma unroll
                for (int c = 0; c < 4; ++c) {
                    float v = acc[j][c] + bv[c];
                    if (RELU) v = fmaxf(v, 0.f);
                    o[c] = v;
                }
                *(f4*)&C[(size_t)r * ldc + coloff + 4 * l] = o;
            }
        }
    } else {
        f2 bv = *(const f2*)&bias[2 * l];
#pragma unroll
        for (int j = 0; j < 8; ++j) {
            int r = row0 + w + 4 * j;
            if (r < n) {
                f2 o;
#pragma unroll
                for (int c = 0; c < 2; ++c) {
                    float v = acc[j][c] + bv[c];
                    if (RELU) v = fmaxf(v, 0.f);
                    o[c] = v;
                }
                *(f2*)&C[(size_t)r * ldc + coloff + 2 * l] = o;
            }
        }
    }
}

// ---------------------------------------------------------------------------
// column-sum (for mean readout): grid-strided row chunks, atomic accumulate
// ---------------------------------------------------------------------------
__global__ void colsum(const float* __restrict__ x, float* __restrict__ mean_out, int n) {
    int rows = (n + gridDim.x - 1) / gridDim.x;
    int r0 = blockIdx.x * rows;
    int r1 = min(r0 + rows, n);
    float s = 0.f;
    for (int r = r0; r < r1; ++r) s += x[(size_t)r * FDIM + threadIdx.x];
    atomicAdd(&mean_out[threadIdx.x], s);
}

// sigmoid(mean) then v = disc_w @ c, for both views. 1 block x 256 threads.
__global__ void disc_prep(const float* __restrict__ means, const float* __restrict__ disc_w,
                          float* __restrict__ vv, float invn) {
    __shared__ float c0[256], c1[256];
    int t = threadIdx.x;
    c0[t] = 1.f / (1.f + expf(-means[t] * invn));
    c1[t] = 1.f / (1.f + expf(-means[256 + t] * invn));
    __syncthreads();
    float v0 = 0.f, v1 = 0.f;
    for (int j = 0; j < 256; ++j) {
        float wv = disc_w[t * 256 + j];
        v0 += wv * c0[j];
        v1 += wv * c1[j];
    }
    vv[t] = v0;
    vv[256 + t] = v1;
}

// 4 bilinear scores per node; one wave per node
__global__ __launch_bounds__(256) void disc_score(
        const float* __restrict__ x2os, const float* __restrict__ x2a,
        const float* __restrict__ vv, const float* __restrict__ disc_b,
        float* __restrict__ ret_os, float* __restrict__ ret_osa, int n) {
    int gw = (blockIdx.x * 256 + threadIdx.x) >> 6;
    int l  = threadIdx.x & 63;
    if (gw >= n) return;
    f4 a  = *(const f4*)&x2os[(size_t)gw * FDIM + 4 * l];
    f4 b  = *(const f4*)&x2a[(size_t)gw * FDIM + 4 * l];
    f4 v0 = *(const f4*)&vv[4 * l];
    f4 v1 = *(const f4*)&vv[256 + 4 * l];
    float d1 = a[0]*v0[0] + a[1]*v0[1] + a[2]*v0[2] + a[3]*v0[3];
    float d2 = b[0]*v0[0] + b[1]*v0[1] + b[2]*v0[2] + b[3]*v0[3];
    float d3 = b[0]*v1[0] + b[1]*v1[1] + b[2]*v1[2] + b[3]*v1[3];
    float d4 = a[0]*v1[0] + a[1]*v1[1] + a[2]*v1[2] + a[3]*v1[3];
    for (int off = 32; off > 0; off >>= 1) {
        d1 += __shfl_down(d1, off);
        d2 += __shfl_down(d2, off);
        d3 += __shfl_down(d3, off);
        d4 += __shfl_down(d4, off);
    }
    if (l == 0) {
        float db = disc_b[0];
        ret_os[2 * gw]      = d1 + db;
        ret_os[2 * gw + 1]  = d2 + db;
        ret_osa[2 * gw]     = d3 + db;
        ret_osa[2 * gw + 1] = d4 + db;
    }
}

// ---------------------------------------------------------------------------
// Fused decoder: out[p] = relu(feat(p) @ W1 + b1) @ W2 + b2
// feat(p) = [e1+e2 | e1*e2 | e1 | e2], e{1,2} = x2_os[idx{0,1}[p]]  (K=1024)
// block = 32 pairs x 512 hidden, 256 threads; wave w owns rows w+4j;
// lane l owns hidden cols {4l..4l+3} and {256+4l..256+4l+3}
// ---------------------------------------------------------------------------
__global__ __launch_bounds__(256) void decoder(
        const float* __restrict__ x2os, const int* __restrict__ idx0,
        const int* __restrict__ idx1, const float* __restrict__ W1,
        const float* __restrict__ b1, const float* __restrict__ W2,
        const float* __restrict__ b2, float* __restrict__ out) {
    __shared__ __align__(16) float Bt[16][512];
    __shared__ __align__(16) float At[32][16];
    __shared__ int i0s[32], i1s[32];
    int t = threadIdx.x;
    int w = t >> 6, l = t & 63;
    int p0 = blockIdx.x * 32;
    if (t < 32)       i0s[t]      = idx0[p0 + t];
    else if (t < 64)  i1s[t - 32] = idx1[p0 + (t - 32)];
    __syncthreads();

    float acc[8][8];
#pragma unroll
    for (int j = 0; j < 8; ++j)
#pragma unroll
        for (int c = 0; c < 8; ++c) acc[j][c] = 0.f;

    for (int kb = 0; kb < 1024; kb += 16) {
        __syncthreads();
        // B tile = contiguous 16 K-rows of W1
        {
            const f4* src = (const f4*)(W1 + (size_t)kb * 512);
            f4* dstp = (f4*)&Bt[0][0];
#pragma unroll
            for (int q = t; q < 16 * 512 / 4; q += 256) dstp[q] = src[q];
        }
        // A tile: generate feat on the fly (2 elements per thread)
        {
            int q = t * 2;
            int r = q >> 4, kk = q & 15;
            int reg = kb >> 8;             // 0:e1+e2  1:e1*e2  2:e1  3:e2
            int fb  = (kb & 255) + kk;     // feature index within 256
            int n1 = i0s[r], n2 = i1s[r];
            f2 e1 = *(const f2*)&x2os[(size_t)n1 * FDIM + fb];
            f2 e2 = *(const f2*)&x2os[(size_t)n2 * FDIM + fb];
            f2 v;
            if (reg == 0)      v = e1 + e2;
            else if (reg == 1) v = e1 * e2;
            else if (reg == 2) v = e1;
            else               v = e2;
            *(f2*)&At[r][kk] = v;
        }
        __syncthreads();
#pragma unroll
        for (int kk4 = 0; kk4 < 16; kk4 += 4) {
            f4 a4[8];
#pragma unroll
            for (int j = 0; j < 8; ++j) a4[j] = *(f4*)&At[w + 4 * j][kk4];
#pragma unroll
            for (int u = 0; u < 4; ++u) {
                f4 bv0 = *(f4*)&Bt[kk4 + u][4 * l];
                f4 bv1 = *(f4*)&Bt[kk4 + u][256 + 4 * l];
#pragma unroll
                for (int j = 0; j < 8; ++j) {
                    float a = a4[j][u];
                    acc[j][0] += a * bv0[0]; acc[j][1] += a * bv0[1];
                    acc[j][2] += a * bv0[2]; acc[j][3] += a * bv0[3];
                    acc[j][4] += a * bv1[0]; acc[j][5] += a * bv1[1];
                    acc[j][6] += a * bv1[2]; acc[j][7] += a * bv1[3];
                }
            }
        }
    }

    // epilogue: relu + bias, dot with W2, wave-reduce per row
    f4 bb0 = *(const f4*)&b1[4 * l];
    f4 bb1 = *(const f4*)&b1[256 + 4 * l];
    f4 w0  = *(const f4*)&W2[4 * l];
    f4 w1v = *(const f4*)&W2[256 + 4 * l];
    float b2s = b2[0];
#pragma unroll
    for (int j = 0; j < 8; ++j) {
        float s = 0.f;
#pragma unroll
        for (int c = 0; c < 4; ++c) s += fmaxf(acc[j][c] + bb0[c], 0.f) * w0[c];
#pragma unroll
        for (int c = 0; c < 4; ++c) s += fmaxf(acc[j][4 + c] + bb1[c], 0.f) * w1v[c];
        for (int off = 32; off > 0; off >>= 1) s += __shfl_down(s, off);
        if (l == 0) out[p0 + w + 4 * j] = s + b2s;
    }
}

// ---------------------------------------------------------------------------
extern "C" void kernel_launch(void* const* d_in, const int* in_sizes, int n_in,
                              void* d_out, int out_size, void* d_ws, size_t ws_size,
                              hipStream_t stream) {
    const float* x_o   = (const float*)d_in[0];
    const float* x_a   = (const float*)d_in[1];
    const int*   ei_o  = (const int*)d_in[2];
    const int*   ei_s  = (const int*)d_in[3];
    const int*   idx   = (const int*)d_in[4];
    const float* eps_o1 = (const float*)d_in[5];
    const float* w1_o1 = (const float*)d_in[6];
    const float* b1_o1 = (const float*)d_in[7];
    const float* w2_o1 = (const float*)d_in[8];
    const float* b2_o1 = (const float*)d_in[9];
    const float* eps_s1 = (const float*)d_in[10];
    const float* w1_s1 = (const float*)d_in[11];
    const float* b1_s1 = (const float*)d_in[12];
    const float* w2_s1 = (const float*)d_in[13];
    const float* b2_s1 = (const float*)d_in[14];
    const float* eps_o2 = (const float*)d_in[15];
    const float* w1_o2 = (const float*)d_in[16];
    const float* b1_o2 = (const float*)d_in[17];
    const float* w2_o2 = (const float*)d_in[18];
    const float* b2_o2 = (const float*)d_in[19];
    const float* eps_s2 = (const float*)d_in[20];
    const float* w1_s2 = (const float*)d_in[21];
    const float* b1_s2 = (const float*)d_in[22];
    const float* w2_s2 = (const float*)d_in[23];
    const float* b2_s2 = (const float*)d_in[24];
    const float* disc_w = (const float*)d_in[25];
    const float* disc_b = (const float*)d_in[26];
    const float* dec1_w = (const float*)d_in[27];
    const float* dec1_b = (const float*)d_in[28];
    const float* dec2_w = (const float*)d_in[29];
    const float* dec2_b = (const float*)d_in[30];

    float* out_log = (float*)d_out;                    // [P]
    float* ret_os  = out_log + PPAIRS;                 // [N,2]
    float* ret_osa = ret_os + 2 * N_NODES;             // [N,2]
    float* x2_os   = ret_osa + 2 * N_NODES;            // [N,256]

    char* wp = (char*)d_ws;
    auto alloc = [&](size_t bytes) -> void* {
        void* p = (void*)wp;
        wp += (bytes + 255) & ~(size_t)255;
        return p;
    };
    int*   rowptr_o = (int*)alloc((N_NODES + 1) * sizeof(int));
    int*   rowptr_s = (int*)alloc((N_NODES + 1) * sizeof(int));
    int*   col_o    = (int*)alloc((size_t)N_EDGES * sizeof(int));
    int*   col_s    = (int*)alloc((size_t)N_EDGES * sizeof(int));
    int*   cursor   = (int*)alloc((size_t)N_NODES * sizeof(int));
    float* hbuf     = (float*)alloc((size_t)N_NODES * FDIM * sizeof(float));
    float* tbuf     = (float*)alloc((size_t)N_NODES * FDIM * sizeof(float));
    float* x1buf    = (float*)alloc((size_t)N_NODES * FDIM * sizeof(float));
    float* x2a      = (float*)alloc((size_t)N_NODES * FDIM * sizeof(float));
    float* means    = (float*)alloc(512 * sizeof(float));
    float* vv       = (float*)alloc(512 * sizeof(float));

    const int EB = (N_EDGES + 255) / 256;

    hipMemsetAsync(means, 0, 512 * sizeof(float), stream);

    // CSR for edge_index_o
    hipMemsetAsync(cursor, 0, N_NODES * sizeof(int), stream);
    count_deg<<<EB, 256, 0, stream>>>(ei_o + N_EDGES, cursor, N_EDGES);
    exclusive_scan<<<1, 1024, 0, stream>>>(cursor, rowptr_o, N_NODES);
    hipMemsetAsync(cursor, 0, N_NODES * sizeof(int), stream);
    fill_csr<<<EB, 256, 0, stream>>>(ei_o, ei_o + N_EDGES, rowptr_o, cursor, col_o, N_EDGES);
    // CSR for edge_index_s
    hipMemsetAsync(cursor, 0, N_NODES * sizeof(int), stream);
    count_deg<<<EB, 256, 0, stream>>>(ei_s + N_EDGES, cursor, N_EDGES);
    exclusive_scan<<<1, 1024, 0, stream>>>(cursor, rowptr_s, N_NODES);
    hipMemsetAsync(cursor, 0, N_NODES * sizeof(int), stream);
    fill_csr<<<EB, 256, 0, stream>>>(ei_s, ei_s + N_EDGES, rowptr_s, cursor, col_s, N_EDGES);

    const int AGGB = (N_NODES + 3) / 4;     // wave per node
    const int GB   = (N_NODES + 31) / 32;   // 32 rows per block

    auto encode = [&](const float* x, float* x2out) {
        // layer 1, conv o -> x1[:, 0:128]
        agg_h<<<AGGB, 256, 0, stream>>>(x, rowptr_o, col_o, eps_o1, hbuf, N_NODES);
        gin_gemm<256, true><<<GB, 256, 0, stream>>>(hbuf, w1_o1, b1_o1, tbuf, N_NODES, 256, 0);
        gin_gemm<128, true><<<GB, 256, 0, stream>>>(tbuf, w2_o1, b2_o1, x1buf, N_NODES, 256, 0);
        // layer 1, conv s -> x1[:, 128:256]
        agg_h<<<AGGB, 256, 0, stream>>>(x, rowptr_s, col_s, eps_s1, hbuf, N_NODES);
        gin_gemm<256, true><<<GB, 256, 0, stream>>>(hbuf, w1_s1, b1_s1, tbuf, N_NODES, 256, 0);
        gin_gemm<128, true><<<GB, 256, 0, stream>>>(tbuf, w2_s1, b2_s1, x1buf, N_NODES, 256, 128);
        // layer 2, conv o -> x2[:, 0:128]   (no relu)
        agg_h<<<AGGB, 256, 0, stream>>>(x1buf, rowptr_o, col_o, eps_o2, hbuf, N_NODES);
        gin_gemm<256, true><<<GB, 256, 0, stream>>>(hbuf, w1_o2, b1_o2, tbuf, N_NODES, 256, 0);
        gin_gemm<128, false><<<GB, 256, 0, stream>>>(tbuf, w2_o2, b2_o2, x2out, N_NODES, 256, 0);
        // layer 2, conv s -> x2[:, 128:256] (no relu)
        agg_h<<<AGGB, 256, 0, stream>>>(x1buf, rowptr_s, col_s, eps_s2, hbuf, N_NODES);
        gin_gemm<256, true><<<GB, 256, 0, stream>>>(hbuf, w1_s2, b1_s2, tbuf, N_NODES, 256, 0);
        gin_gemm<128, false><<<GB, 256, 0, stream>>>(tbuf, w2_s2, b2_s2, x2out, N_NODES, 256, 128);
    };

    encode(x_o, x2_os);
    encode(x_a, x2a);

    colsum<<<128, 256, 0, stream>>>(x2_os, means, N_NODES);
    colsum<<<128, 256, 0, stream>>>(x2a, means + 256, N_NODES);
    disc_prep<<<1, 256, 0, stream>>>(means, disc_w, vv, 1.0f / (float)N_NODES);
    disc_score<<<(N_NODES + 3) / 4, 256, 0, stream>>>(x2_os, x2a, vv, disc_b,
                                                      ret_os, ret_osa, N_NODES);
    decoder<<<PPAIRS / 32, 256, 0, stream>>>(x2_os, idx, idx + PPAIRS,
                                             dec1_w, dec1_b, dec2_w, dec2_b, out_log);
}

// Round 3
// 2445.013 us; speedup vs baseline: 1.7738x; 1.7738x over previous
//
#include <hip/hip_runtime.h>
#include <hip/hip_bf16.h>
#include <stdint.h>

#define N_NODES 50000
#define N_EDGES 400000
#define FDIM    256
#define PPAIRS  100000

typedef float f4 __attribute__((ext_vector_type(4)));
typedef float f2 __attribute__((ext_vector_type(2)));
typedef short s8v __attribute__((ext_vector_type(8)));
typedef float f32x4 __attribute__((ext_vector_type(4)));
typedef unsigned short u16;

__device__ inline u16 f2bf(float v) {
    union { float f; uint32_t u; } x; x.f = v;
    uint32_t r = x.u + 0x7fffu + ((x.u >> 16) & 1u);   // RNE
    return (u16)(r >> 16);
}
__device__ inline float bf2f(u16 b) {
    union { uint32_t u; float f; } x; x.u = ((uint32_t)b) << 16;
    return x.f;
}
__device__ inline f32x4 mfma16(s8v a, s8v b, f32x4 c) {
    return __builtin_amdgcn_mfma_f32_16x16x32_bf16(a, b, c, 0, 0, 0);
}

// ---------------------------------------------------------------------------
// CSR construction
// ---------------------------------------------------------------------------
__global__ void count_deg(const int* __restrict__ dst, int* __restrict__ deg, int e) {
    int t = blockIdx.x * blockDim.x + threadIdx.x;
    if (t < e) atomicAdd(&deg[dst[t]], 1);
}

__global__ void exclusive_scan(const int* __restrict__ deg, int* __restrict__ rowptr, int n) {
    __shared__ int sums[1024];
    int t = threadIdx.x;
    int chunk = (n + 1023) >> 10;
    int begin = t * chunk;
    int end   = min(begin + chunk, n);
    int s = 0;
    for (int i = begin; i < end; ++i) s += deg[i];
    sums[t] = s;
    __syncthreads();
    for (int off = 1; off < 1024; off <<= 1) {
        int v = (t >= off) ? sums[t - off] : 0;
        __syncthreads();
        sums[t] += v;
        __syncthreads();
    }
    int prefix = (t == 0) ? 0 : sums[t - 1];
    for (int i = begin; i < end; ++i) { rowptr[i] = prefix; prefix += deg[i]; }
    if (t == 1023) rowptr[n] = sums[1023];
}

__global__ void fill_csr(const int* __restrict__ src, const int* __restrict__ dst,
                         const int* __restrict__ rowptr, int* __restrict__ cursor,
                         int* __restrict__ col, int e) {
    int t = blockIdx.x * blockDim.x + threadIdx.x;
    if (t < e) {
        int d = dst[t];
        int pos = atomicAdd(&cursor[d], 1);
        col[rowptr[d] + pos] = src[t];
    }
}

// ---------------------------------------------------------------------------
// GIN aggregation: h = (1+eps)*x + sum_neighbors x  -> split bf16 (hi, lo)
// ---------------------------------------------------------------------------
__global__ __launch_bounds__(256) void agg_h_split(
        const float* __restrict__ x, const int* __restrict__ rowptr,
        const int* __restrict__ col, const float* __restrict__ eps,
        u16* __restrict__ hh, u16* __restrict__ hl, int n) {
    int gw = (blockIdx.x * 256 + threadIdx.x) >> 6;
    int l  = threadIdx.x & 63;
    if (gw >= n) return;
    float e = 1.0f + eps[0];
    f4 acc = {0.f, 0.f, 0.f, 0.f};
    int b0 = rowptr[gw], b1 = rowptr[gw + 1];
    for (int i = b0; i < b1; ++i) {
        int s = col[i];
        acc += *(const f4*)&x[(size_t)s * FDIM + 4 * l];
    }
    f4 self = *(const f4*)&x[(size_t)gw * FDIM + 4 * l];
    f4 r = e * self + acc;
    u16 hb[4], lb[4];
#pragma unroll
    for (int c = 0; c < 4; ++c) {
        hb[c] = f2bf(r[c]);
        lb[c] = f2bf(r[c] - bf2f(hb[c]));
    }
    uint2 hv, lv;
    hv.x = (uint32_t)hb[0] | ((uint32_t)hb[1] << 16);
    hv.y = (uint32_t)hb[2] | ((uint32_t)hb[3] << 16);
    lv.x = (uint32_t)lb[0] | ((uint32_t)lb[1] << 16);
    lv.y = (uint32_t)lb[2] | ((uint32_t)lb[3] << 16);
    *(uint2*)&hh[(size_t)gw * FDIM + 4 * l] = hv;
    *(uint2*)&hl[(size_t)gw * FDIM + 4 * l] = lv;
}

// ---------------------------------------------------------------------------
// Weight prep: split fp32 W[K][Nc] -> bf16 hi/lo, k-grouped layout
// dst[(k>>3)*Nc*8 + n*8 + (k&7)]
// ---------------------------------------------------------------------------
__global__ void split_w(const float* __restrict__ W, u16* __restrict__ Wh,
                        u16* __restrict__ Wl, int K, int Nc) {
    int t = blockIdx.x * 256 + threadIdx.x;
    if (t >= K * Nc) return;
    int k = t / Nc, c = t - k * Nc;
    float v = W[t];
    u16 h = f2bf(v);
    u16 lo = f2bf(v - bf2f(h));
    int dst = ((k >> 3) * Nc + c) * 8 + (k & 7);
    Wh[dst] = h; Wl[dst] = lo;
}

// decoder weight combine: W'[768][512]
//   rows 0:256 = Wa+Wc (e1), 256:512 = Wa+Wd (e2), 512:768 = Wb (e1*e2)
__global__ void prep_decw(const float* __restrict__ w1, u16* __restrict__ Wh,
                          u16* __restrict__ Wl) {
    int t = blockIdx.x * 256 + threadIdx.x;
    if (t >= 768 * 512) return;
    int k = t >> 9, c = t & 511;
    float v;
    if (k < 256)       v = w1[(size_t)k * 512 + c] + w1[(size_t)(512 + k) * 512 + c];
    else if (k < 512)  v = w1[(size_t)(k - 256) * 512 + c] + w1[(size_t)(768 + k - 256) * 512 + c];
    else               v = w1[(size_t)(256 + k - 512) * 512 + c];
    u16 h = f2bf(v);
    u16 lo = f2bf(v - bf2f(h));
    int dst = ((k >> 3) * 512 + c) * 8 + (k & 7);
    Wh[dst] = h; Wl[dst] = lo;
}

// ---------------------------------------------------------------------------
// split-bf16 MFMA GEMM: C[128x128 per block] = A[.,256] @ W[256,nout]
// ---------------------------------------------------------------------------
template <int EPI, bool RELU>
__global__ __launch_bounds__(512) void mfma_gemm(
        const u16* __restrict__ Ah, const u16* __restrict__ Al,
        const u16* __restrict__ Bh, const u16* __restrict__ Bl,
        const float* __restrict__ bias,
        u16* __restrict__ Ch, u16* __restrict__ Cl,
        float* __restrict__ Cf, int ldc, int coloff,
        int n, int nout) {
    __shared__ __align__(16) u16 As[2][2][4][128][8];   // [buf][hl][kg][row][j]
    __shared__ __align__(16) u16 Bs[2][2][4][128][8];   // [buf][hl][kg][col][j]
    int t = threadIdx.x;
    int w = t >> 6, lm = t & 15, lg = (t >> 4) & 3;
    int row0 = blockIdx.x * 128;
    int c0   = blockIdx.y * 128;
    int srow = t & 127, skg = (t >> 7) & 3;

    int garow = min(row0 + srow, n - 1);
    const u16* gAh = Ah + (size_t)garow * 256 + skg * 8;
    const u16* gAl = Al + (size_t)garow * 256 + skg * 8;
    const u16* gBh = Bh + ((size_t)skg * nout + c0 + srow) * 8;
    const u16* gBl = Bl + ((size_t)skg * nout + c0 + srow) * 8;
    const size_t bstep = (size_t)4 * nout * 8;

    f32x4 acc[8] = {};
    uint4 rAh, rAl, rBh, rBl;

    rAh = *(const uint4*)(gAh);
    rAl = *(const uint4*)(gAl);
    rBh = *(const uint4*)(gBh);
    rBl = *(const uint4*)(gBl);
    *(uint4*)&As[0][0][skg][srow][0] = rAh;
    *(uint4*)&As[0][1][skg][srow][0] = rAl;
    *(uint4*)&Bs[0][0][skg][srow][0] = rBh;
    *(uint4*)&Bs[0][1][skg][srow][0] = rBl;
    __syncthreads();

    int cur = 0;
#pragma unroll
    for (int c = 0; c < 8; ++c) {
        if (c < 7) {   // T14: issue next-chunk loads early
            rAh = *(const uint4*)(gAh + (c + 1) * 32);
            rAl = *(const uint4*)(gAl + (c + 1) * 32);
            rBh = *(const uint4*)(gBh + (c + 1) * bstep);
            rBl = *(const uint4*)(gBl + (c + 1) * bstep);
        }
        s8v bh = *(const s8v*)&Bs[cur][0][lg][w * 16 + lm][0];
        s8v bl = *(const s8v*)&Bs[cur][1][lg][w * 16 + lm][0];
#pragma unroll
        for (int R = 0; R < 8; R += 2) {
            s8v ah0 = *(const s8v*)&As[cur][0][lg][R * 16 + lm][0];
            s8v al0 = *(const s8v*)&As[cur][1][lg][R * 16 + lm][0];
            s8v ah1 = *(const s8v*)&As[cur][0][lg][(R + 1) * 16 + lm][0];
            s8v al1 = *(const s8v*)&As[cur][1][lg][(R + 1) * 16 + lm][0];
            acc[R]     = mfma16(ah0, bh, acc[R]);
            acc[R + 1] = mfma16(ah1, bh, acc[R + 1]);
            acc[R]     = mfma16(ah0, bl, acc[R]);
            acc[R + 1] = mfma16(ah1, bl, acc[R + 1]);
            acc[R]     = mfma16(al0, bh, acc[R]);
            acc[R + 1] = mfma16(al1, bh, acc[R + 1]);
        }
        if (c < 7) {   // write-late
            int nb = cur ^ 1;
            *(uint4*)&As[nb][0][skg][srow][0] = rAh;
            *(uint4*)&As[nb][1][skg][srow][0] = rAl;
            *(uint4*)&Bs[nb][0][skg][srow][0] = rBh;
            *(uint4*)&Bs[nb][1][skg][srow][0] = rBl;
        }
        __syncthreads();
        cur ^= 1;
    }

    int cg = c0 + w * 16 + lm;
    float bv = bias[cg];
#pragma unroll
    for (int R = 0; R < 8; ++R) {
#pragma unroll
        for (int i = 0; i < 4; ++i) {
            int r = row0 + R * 16 + lg * 4 + i;
            if (r < n) {
                float v = acc[R][i] + bv;
                if (RELU) v = fmaxf(v, 0.f);
                if (EPI == 0) {
                    u16 hbv = f2bf(v);
                    Ch[(size_t)r * 256 + cg] = hbv;
                    Cl[(size_t)r * 256 + cg] = f2bf(v - bf2f(hbv));
                } else {
                    Cf[(size_t)r * ldc + coloff + cg] = v;
                }
            }
        }
    }
}

// ---------------------------------------------------------------------------
// Fused decoder (MFMA): hidden = e1@(Wa+Wc) + e2@(Wa+Wd) + (e1*e2)@Wb  (K=768)
// partial[p][cb][w]: per-wave 16-col partial of relu(hidden+b1)@w2.
// block: 128 pairs x 128 hidden cols, grid.y = 4 col-blocks.
// ---------------------------------------------------------------------------
__global__ __launch_bounds__(512) void decoder_mfma(
        const float* __restrict__ x2os, const int* __restrict__ idx0,
        const int* __restrict__ idx1,
        const u16* __restrict__ Wh, const u16* __restrict__ Wl,   // [96][512][8]
        const float* __restrict__ b1, const float* __restrict__ w2,
        float* __restrict__ partial) {
    __shared__ __align__(16) u16 As[2][2][4][128][8];
    __shared__ __align__(16) u16 Bs[2][2][4][128][8];
    int t = threadIdx.x;
    int w = t >> 6, lm = t & 15, lg = (t >> 4) & 3;
    int p0 = blockIdx.x * 128;
    int c0 = blockIdx.y * 128;
    int srow = t & 127, skg = (t >> 7) & 3;

    int p = min(p0 + srow, PPAIRS - 1);
    int n1 = idx0[p], n2 = idx1[p];
    const float* e1p = x2os + (size_t)n1 * 256;
    const float* e2p = x2os + (size_t)n2 * 256;
    const u16* gBh = Wh + ((size_t)skg * 512 + c0 + srow) * 8;
    const u16* gBl = Wl + ((size_t)skg * 512 + c0 + srow) * 8;
    const size_t bstep = (size_t)4 * 512 * 8;

    f32x4 acc[8] = {};
    f4 r1a, r1b, r2a, r2b;
    uint4 rBh, rBl;

    auto loadA = [&](int c) {
        int kb = c * 32;
        int reg = kb >> 8;
        int fb = (kb & 255) + skg * 8;
        if (reg == 0)      { r1a = *(const f4*)(e1p + fb); r1b = *(const f4*)(e1p + fb + 4); }
        else if (reg == 1) { r1a = *(const f4*)(e2p + fb); r1b = *(const f4*)(e2p + fb + 4); }
        else {               r1a = *(const f4*)(e1p + fb); r1b = *(const f4*)(e1p + fb + 4);
                             r2a = *(const f4*)(e2p + fb); r2b = *(const f4*)(e2p + fb + 4); }
    };
    auto writeA = [&](int nb, int c) {
        int reg = (c * 32) >> 8;
        float v[8];
#pragma unroll
        for (int q = 0; q < 4; ++q) { v[q] = r1a[q]; v[4 + q] = r1b[q]; }
        if (reg == 2) {
#pragma unroll
            for (int q = 0; q < 4; ++q) { v[q] *= r2a[q]; v[4 + q] *= r2b[q]; }
        }
        u16 hb[8], lb[8];
#pragma unroll
        for (int q = 0; q < 8; ++q) { hb[q] = f2bf(v[q]); lb[q] = f2bf(v[q] - bf2f(hb[q])); }
        uint4 hv, lv;
        hv.x = (uint32_t)hb[0] | ((uint32_t)hb[1] << 16);
        hv.y = (uint32_t)hb[2] | ((uint32_t)hb[3] << 16);
        hv.z = (uint32_t)hb[4] | ((uint32_t)hb[5] << 16);
        hv.w = (uint32_t)hb[6] | ((uint32_t)hb[7] << 16);
        lv.x = (uint32_t)lb[0] | ((uint32_t)lb[1] << 16);
        lv.y = (uint32_t)lb[2] | ((uint32_t)lb[3] << 16);
        lv.z = (uint32_t)lb[4] | ((uint32_t)lb[5] << 16);
        lv.w = (uint32_t)lb[6] | ((uint32_t)lb[7] << 16);
        *(uint4*)&As[nb][0][skg][srow][0] = hv;
        *(uint4*)&As[nb][1][skg][srow][0] = lv;
    };

    loadA(0);
    rBh = *(const uint4*)(gBh);
    rBl = *(const uint4*)(gBl);
    writeA(0, 0);
    *(uint4*)&Bs[0][0][skg][srow][0] = rBh;
    *(uint4*)&Bs[0][1][skg][srow][0] = rBl;
    __syncthreads();

    int cur = 0;
#pragma unroll
    for (int c = 0; c < 24; ++c) {
        if (c < 23) {
            loadA(c + 1);
            rBh = *(const uint4*)(gBh + (c + 1) * bstep);
            rBl = *(const uint4*)(gBl + (c + 1) * bstep);
        }
        s8v bh = *(const s8v*)&Bs[cur][0][lg][w * 16 + lm][0];
        s8v bl = *(const s8v*)&Bs[cur][1][lg][w * 16 + lm][0];
#pragma unroll
        for (int R = 0; R < 8; R += 2) {
            s8v ah0 = *(const s8v*)&As[cur][0][lg][R * 16 + lm][0];
            s8v al0 = *(const s8v*)&As[cur][1][lg][R * 16 + lm][0];
            s8v ah1 = *(const s8v*)&As[cur][0][lg][(R + 1) * 16 + lm][0];
            s8v al1 = *(const s8v*)&As[cur][1][lg][(R + 1) * 16 + lm][0];
            acc[R]     = mfma16(ah0, bh, acc[R]);
            acc[R + 1] = mfma16(ah1, bh, acc[R + 1]);
            acc[R]     = mfma16(ah0, bl, acc[R]);
            acc[R + 1] = mfma16(ah1, bl, acc[R + 1]);
            acc[R]     = mfma16(al0, bh, acc[R]);
            acc[R + 1] = mfma16(al1, bh, acc[R + 1]);
        }
        if (c < 23) {
            int nb = cur ^ 1;
            writeA(nb, c + 1);
            *(uint4*)&Bs[nb][0][skg][srow][0] = rBh;
            *(uint4*)&Bs[nb][1][skg][srow][0] = rBl;
        }
        __syncthreads();
        cur ^= 1;
    }

    // epilogue: relu+bias, dot with w2 over this wave's 16 cols;
    // FIX: per-wave partial slot (was: 8 waves clobbering one slot)
    int cg = c0 + w * 16 + lm;
    float bv = b1[cg], w2v = w2[cg];
    int cb = blockIdx.y;
#pragma unroll
    for (int R = 0; R < 8; ++R) {
#pragma unroll
        for (int i = 0; i < 4; ++i) {
            float v = fmaxf(acc[R][i] + bv, 0.f) * w2v;
            v += __shfl_xor(v, 1);
            v += __shfl_xor(v, 2);
            v += __shfl_xor(v, 4);
            v += __shfl_xor(v, 8);
            if (lm == 0) {
                int pr = p0 + R * 16 + lg * 4 + i;
                if (pr < PPAIRS) partial[(size_t)pr * 32 + cb * 8 + w] = v;
            }
        }
    }
}

__global__ void finalize_out(const float* __restrict__ partial,
                             const float* __restrict__ b2, float* __restrict__ out) {
    int p = blockIdx.x * 256 + threadIdx.x;
    if (p < PPAIRS) {
        float s = 0.f;
#pragma unroll
        for (int q = 0; q < 8; ++q) {
            f4 v = *(const f4*)&partial[(size_t)p * 32 + q * 4];
            s += v[0] + v[1] + v[2] + v[3];
        }
        out[p] = s + b2[0];
    }
}

// ---------------------------------------------------------------------------
// readout / discriminator (fp32, cheap)
// ---------------------------------------------------------------------------
__global__ void colsum(const float* __restrict__ x, float* __restrict__ mean_out, int n) {
    int rows = (n + gridDim.x - 1) / gridDim.x;
    int r0 = blockIdx.x * rows;
    int r1 = min(r0 + rows, n);
    float s = 0.f;
    for (int r = r0; r < r1; ++r) s += x[(size_t)r * FDIM + threadIdx.x];
    atomicAdd(&mean_out[threadIdx.x], s);
}

__global__ void disc_prep(const float* __restrict__ means, const float* __restrict__ disc_w,
                          float* __restrict__ vv, float invn) {
    __shared__ float c0[256], c1[256];
    int t = threadIdx.x;
    c0[t] = 1.f / (1.f + expf(-means[t] * invn));
    c1[t] = 1.f / (1.f + expf(-means[256 + t] * invn));
    __syncthreads();
    float v0 = 0.f, v1 = 0.f;
    for (int j = 0; j < 256; ++j) {
        float wv = disc_w[t * 256 + j];
        v0 += wv * c0[j];
        v1 += wv * c1[j];
    }
    vv[t] = v0;
    vv[256 + t] = v1;
}

__global__ __launch_bounds__(256) void disc_score(
        const float* __restrict__ x2os, const float* __restrict__ x2a,
        const float* __restrict__ vv, const float* __restrict__ disc_b,
        float* __restrict__ ret_os, float* __restrict__ ret_osa, int n) {
    int gw = (blockIdx.x * 256 + threadIdx.x) >> 6;
    int l  = threadIdx.x & 63;
    if (gw >= n) return;
    f4 a  = *(const f4*)&x2os[(size_t)gw * FDIM + 4 * l];
    f4 b  = *(const f4*)&x2a[(size_t)gw * FDIM + 4 * l];
    f4 v0 = *(const f4*)&vv[4 * l];
    f4 v1 = *(const f4*)&vv[256 + 4 * l];
    float d1 = a[0]*v0[0] + a[1]*v0[1] + a[2]*v0[2] + a[3]*v0[3];
    float d2 = b[0]*v0[0] + b[1]*v0[1] + b[2]*v0[2] + b[3]*v0[3];
    float d3 = b[0]*v1[0] + b[1]*v1[1] + b[2]*v1[2] + b[3]*v1[3];
    float d4 = a[0]*v1[0] + a[1]*v1[1] + a[2]*v1[2] + a[3]*v1[3];
    for (int off = 32; off > 0; off >>= 1) {
        d1 += __shfl_down(d1, off);
        d2 += __shfl_down(d2, off);
        d3 += __shfl_down(d3, off);
        d4 += __shfl_down(d4, off);
    }
    if (l == 0) {
        float db = disc_b[0];
        ret_os[2 * gw]      = d1 + db;
        ret_os[2 * gw + 1]  = d2 + db;
        ret_osa[2 * gw]     = d3 + db;
        ret_osa[2 * gw + 1] = d4 + db;
    }
}

// ---------------------------------------------------------------------------
extern "C" void kernel_launch(void* const* d_in, const int* in_sizes, int n_in,
                              void* d_out, int out_size, void* d_ws, size_t ws_size,
                              hipStream_t stream) {
    const float* x_o   = (const float*)d_in[0];
    const float* x_a   = (const float*)d_in[1];
    const int*   ei_o  = (const int*)d_in[2];
    const int*   ei_s  = (const int*)d_in[3];
    const int*   idx   = (const int*)d_in[4];
    const float* eps_o1 = (const float*)d_in[5];
    const float* w1_o1 = (const float*)d_in[6];
    const float* b1_o1 = (const float*)d_in[7];
    const float* w2_o1 = (const float*)d_in[8];
    const float* b2_o1 = (const float*)d_in[9];
    const float* eps_s1 = (const float*)d_in[10];
    const float* w1_s1 = (const float*)d_in[11];
    const float* b1_s1 = (const float*)d_in[12];
    const float* w2_s1 = (const float*)d_in[13];
    const float* b2_s1 = (const float*)d_in[14];
    const float* eps_o2 = (const float*)d_in[15];
    const float* w1_o2 = (const float*)d_in[16];
    const float* b1_o2 = (const float*)d_in[17];
    const float* w2_o2 = (const float*)d_in[18];
    const float* b2_o2 = (const float*)d_in[19];
    const float* eps_s2 = (const float*)d_in[20];
    const float* w1_s2 = (const float*)d_in[21];
    const float* b1_s2 = (const float*)d_in[22];
    const float* w2_s2 = (const float*)d_in[23];
    const float* b2_s2 = (const float*)d_in[24];
    const float* disc_w = (const float*)d_in[25];
    const float* disc_b = (const float*)d_in[26];
    const float* dec1_w = (const float*)d_in[27];
    const float* dec1_b = (const float*)d_in[28];
    const float* dec2_w = (const float*)d_in[29];
    const float* dec2_b = (const float*)d_in[30];

    float* out_log = (float*)d_out;
    float* ret_os  = out_log + PPAIRS;
    float* ret_osa = ret_os + 2 * N_NODES;
    float* x2_os   = ret_osa + 2 * N_NODES;

    char* wp = (char*)d_ws;
    auto alloc = [&](size_t bytes) -> void* {
        void* p = (void*)wp;
        wp += (bytes + 255) & ~(size_t)255;
        return p;
    };
    int*   rowptr_o = (int*)alloc((N_NODES + 1) * sizeof(int));
    int*   rowptr_s = (int*)alloc((N_NODES + 1) * sizeof(int));
    int*   col_o    = (int*)alloc((size_t)N_EDGES * sizeof(int));
    int*   col_s    = (int*)alloc((size_t)N_EDGES * sizeof(int));
    int*   cursor   = (int*)alloc((size_t)N_NODES * sizeof(int));
    u16*   hh       = (u16*)alloc((size_t)N_NODES * FDIM * 2);
    u16*   hl       = (u16*)alloc((size_t)N_NODES * FDIM * 2);
    u16*   th       = (u16*)alloc((size_t)N_NODES * FDIM * 2);
    u16*   tl       = (u16*)alloc((size_t)N_NODES * FDIM * 2);
    float* x1buf    = (float*)alloc((size_t)N_NODES * FDIM * sizeof(float));
    float* x2a      = (float*)alloc((size_t)N_NODES * FDIM * sizeof(float));
    float* partial  = (float*)alloc((size_t)PPAIRS * 32 * sizeof(float));
    float* means    = (float*)alloc(512 * sizeof(float));
    float* vv       = (float*)alloc(512 * sizeof(float));
    u16* w1h[4]; u16* w1l[4]; u16* w2h[4]; u16* w2l[4];
    for (int i = 0; i < 4; ++i) {
        w1h[i] = (u16*)alloc(256 * 256 * 2); w1l[i] = (u16*)alloc(256 * 256 * 2);
        w2h[i] = (u16*)alloc(256 * 128 * 2); w2l[i] = (u16*)alloc(256 * 128 * 2);
    }
    u16* decWh = (u16*)alloc(768 * 512 * 2);
    u16* decWl = (u16*)alloc(768 * 512 * 2);

    const int EB = (N_EDGES + 255) / 256;
    hipMemsetAsync(means, 0, 512 * sizeof(float), stream);

    // CSR (o)
    hipMemsetAsync(cursor, 0, N_NODES * sizeof(int), stream);
    count_deg<<<EB, 256, 0, stream>>>(ei_o + N_EDGES, cursor, N_EDGES);
    exclusive_scan<<<1, 1024, 0, stream>>>(cursor, rowptr_o, N_NODES);
    hipMemsetAsync(cursor, 0, N_NODES * sizeof(int), stream);
    fill_csr<<<EB, 256, 0, stream>>>(ei_o, ei_o + N_EDGES, rowptr_o, cursor, col_o, N_EDGES);
    // CSR (s)
    hipMemsetAsync(cursor, 0, N_NODES * sizeof(int), stream);
    count_deg<<<EB, 256, 0, stream>>>(ei_s + N_EDGES, cursor, N_EDGES);
    exclusive_scan<<<1, 1024, 0, stream>>>(cursor, rowptr_s, N_NODES);
    hipMemsetAsync(cursor, 0, N_NODES * sizeof(int), stream);
    fill_csr<<<EB, 256, 0, stream>>>(ei_s, ei_s + N_EDGES, rowptr_s, cursor, col_s, N_EDGES);

    // weight prep
    const float* w1s[4] = {w1_o1, w1_s1, w1_o2, w1_s2};
    const float* w2s[4] = {w2_o1, w2_s1, w2_o2, w2_s2};
    for (int i = 0; i < 4; ++i) {
        split_w<<<(256 * 256 + 255) / 256, 256, 0, stream>>>(w1s[i], w1h[i], w1l[i], 256, 256);
        split_w<<<(256 * 128 + 255) / 256, 256, 0, stream>>>(w2s[i], w2h[i], w2l[i], 256, 128);
    }
    prep_decw<<<(768 * 512 + 255) / 256, 256, 0, stream>>>(dec1_w, decWh, decWl);

    const int AGGB = (N_NODES + 3) / 4;
    const int RB   = (N_NODES + 127) / 128;   // 391

    auto conv = [&](const float* xin, const int* rp, const int* cl, const float* epsv,
                    int wi, const float* b1v, const float* b2v,
                    float* outbuf, int coloff, bool relu2) {
        agg_h_split<<<AGGB, 256, 0, stream>>>(xin, rp, cl, epsv, hh, hl, N_NODES);
        mfma_gemm<0, true><<<dim3(RB, 2), 512, 0, stream>>>(
            hh, hl, w1h[wi], w1l[wi], b1v, th, tl, nullptr, 0, 0, N_NODES, 256);
        if (relu2)
            mfma_gemm<1, true><<<dim3(RB, 1), 512, 0, stream>>>(
                th, tl, w2h[wi], w2l[wi], b2v, nullptr, nullptr, outbuf, 256, coloff, N_NODES, 128);
        else
            mfma_gemm<1, false><<<dim3(RB, 1), 512, 0, stream>>>(
                th, tl, w2h[wi], w2l[wi], b2v, nullptr, nullptr, outbuf, 256, coloff, N_NODES, 128);
    };

    auto encode = [&](const float* x, float* x2out) {
        conv(x,     rowptr_o, col_o, eps_o1, 0, b1_o1, b2_o1, x1buf, 0,   true);
        conv(x,     rowptr_s, col_s, eps_s1, 1, b1_s1, b2_s1, x1buf, 128, true);
        conv(x1buf, rowptr_o, col_o, eps_o2, 2, b1_o2, b2_o2, x2out, 0,   false);
        conv(x1buf, rowptr_s, col_s, eps_s2, 3, b1_s2, b2_s2, x2out, 128, false);
    };

    encode(x_o, x2_os);
    encode(x_a, x2a);

    colsum<<<128, 256, 0, stream>>>(x2_os, means, N_NODES);
    colsum<<<128, 256, 0, stream>>>(x2a, means + 256, N_NODES);
    disc_prep<<<1, 256, 0, stream>>>(means, disc_w, vv, 1.0f / (float)N_NODES);
    disc_score<<<(N_NODES + 3) / 4, 256, 0, stream>>>(x2_os, x2a, vv, disc_b,
                                                      ret_os, ret_osa, N_NODES);

    const int DB = (PPAIRS + 127) / 128;   // 782
    decoder_mfma<<<dim3(DB, 4), 512, 0, stream>>>(x2_os, idx, idx + PPAIRS,
                                                  decWh, decWl, dec1_b, dec2_w, partial);
    finalize_out<<<(PPAIRS + 255) / 256, 256, 0, stream>>>(partial, dec2_b, out_log);
}

// Round 5
// 2226.459 us; speedup vs baseline: 1.9479x; 1.0982x over previous
//
#include <hip/hip_runtime.h>
#include <hip/hip_bf16.h>
#include <stdint.h>

#define N_NODES 50000
#define N_EDGES 400000
#define FDIM    256
#define PPAIRS  100000

typedef float f4 __attribute__((ext_vector_type(4)));
typedef float f2 __attribute__((ext_vector_type(2)));
typedef short s8v __attribute__((ext_vector_type(8)));
typedef float f32x4 __attribute__((ext_vector_type(4)));
typedef unsigned short u16;

__device__ inline u16 f2bf(float v) {
    union { float f; uint32_t u; } x; x.f = v;
    uint32_t r = x.u + 0x7fffu + ((x.u >> 16) & 1u);   // RNE
    return (u16)(r >> 16);
}
__device__ inline float bf2f(u16 b) {
    union { uint32_t u; float f; } x; x.u = ((uint32_t)b) << 16;
    return x.f;
}
__device__ inline f32x4 mfma16(s8v a, s8v b, f32x4 c) {
    return __builtin_amdgcn_mfma_f32_16x16x32_bf16(a, b, c, 0, 0, 0);
}

// ---------------------------------------------------------------------------
// CSR construction
// ---------------------------------------------------------------------------
__global__ void count_deg(const int* __restrict__ dst, int* __restrict__ deg, int e) {
    int t = blockIdx.x * blockDim.x + threadIdx.x;
    if (t < e) atomicAdd(&deg[dst[t]], 1);
}

__global__ void exclusive_scan(const int* __restrict__ deg, int* __restrict__ rowptr, int n) {
    __shared__ int sums[1024];
    int t = threadIdx.x;
    int chunk = (n + 1023) >> 10;
    int begin = t * chunk;
    int end   = min(begin + chunk, n);
    int s = 0;
    for (int i = begin; i < end; ++i) s += deg[i];
    sums[t] = s;
    __syncthreads();
    for (int off = 1; off < 1024; off <<= 1) {
        int v = (t >= off) ? sums[t - off] : 0;
        __syncthreads();
        sums[t] += v;
        __syncthreads();
    }
    int prefix = (t == 0) ? 0 : sums[t - 1];
    for (int i = begin; i < end; ++i) { rowptr[i] = prefix; prefix += deg[i]; }
    if (t == 1023) rowptr[n] = sums[1023];
}

__global__ void fill_csr(const int* __restrict__ src, const int* __restrict__ dst,
                         const int* __restrict__ rowptr, int* __restrict__ cursor,
                         int* __restrict__ col, int e) {
    int t = blockIdx.x * blockDim.x + threadIdx.x;
    if (t < e) {
        int d = dst[t];
        int pos = atomicAdd(&cursor[d], 1);
        col[rowptr[d] + pos] = src[t];
    }
}

// ---------------------------------------------------------------------------
// GIN aggregation: h = (1+eps)*x + sum_neighbors x  -> split bf16 (hi, lo)
// one wave per node; 4-way unrolled neighbor loop for load ILP
// ---------------------------------------------------------------------------
__global__ __launch_bounds__(256) void agg_h_split(
        const float* __restrict__ x, const int* __restrict__ rowptr,
        const int* __restrict__ col, const float* __restrict__ eps,
        u16* __restrict__ hh, u16* __restrict__ hl, int n) {
    int gw = (blockIdx.x * 256 + threadIdx.x) >> 6;
    int l  = threadIdx.x & 63;
    if (gw >= n) return;
    float e = 1.0f + eps[0];
    int b0 = rowptr[gw], b1 = rowptr[gw + 1];
    f4 a0 = {0.f, 0.f, 0.f, 0.f}, a1 = a0, a2 = a0, a3 = a0;
    int i = b0;
    for (; i + 4 <= b1; i += 4) {
        int s0 = col[i], s1 = col[i + 1], s2 = col[i + 2], s3 = col[i + 3];
        f4 v0 = *(const f4*)&x[(size_t)s0 * FDIM + 4 * l];
        f4 v1 = *(const f4*)&x[(size_t)s1 * FDIM + 4 * l];
        f4 v2 = *(const f4*)&x[(size_t)s2 * FDIM + 4 * l];
        f4 v3 = *(const f4*)&x[(size_t)s3 * FDIM + 4 * l];
        a0 += v0; a1 += v1; a2 += v2; a3 += v3;
    }
    for (; i < b1; ++i) {
        int s = col[i];
        a0 += *(const f4*)&x[(size_t)s * FDIM + 4 * l];
    }
    f4 self = *(const f4*)&x[(size_t)gw * FDIM + 4 * l];
    f4 r = e * self + ((a0 + a1) + (a2 + a3));
    u16 hb[4], lb[4];
#pragma unroll
    for (int c = 0; c < 4; ++c) {
        hb[c] = f2bf(r[c]);
        lb[c] = f2bf(r[c] - bf2f(hb[c]));
    }
    uint2 hv, lv;
    hv.x = (uint32_t)hb[0] | ((uint32_t)hb[1] << 16);
    hv.y = (uint32_t)hb[2] | ((uint32_t)hb[3] << 16);
    lv.x = (uint32_t)lb[0] | ((uint32_t)lb[1] << 16);
    lv.y = (uint32_t)lb[2] | ((uint32_t)lb[3] << 16);
    *(uint2*)&hh[(size_t)gw * FDIM + 4 * l] = hv;
    *(uint2*)&hl[(size_t)gw * FDIM + 4 * l] = lv;
}

// ---------------------------------------------------------------------------
// Weight prep: split fp32 W[K][Nc] -> bf16 hi/lo, k-grouped layout
// dst[(k>>3)*Nc*8 + n*8 + (k&7)]
// ---------------------------------------------------------------------------
__global__ void split_w(const float* __restrict__ W, u16* __restrict__ Wh,
                        u16* __restrict__ Wl, int K, int Nc) {
    int t = blockIdx.x * 256 + threadIdx.x;
    if (t >= K * Nc) return;
    int k = t / Nc, c = t - k * Nc;
    float v = W[t];
    u16 h = f2bf(v);
    u16 lo = f2bf(v - bf2f(h));
    int dst = ((k >> 3) * Nc + c) * 8 + (k & 7);
    Wh[dst] = h; Wl[dst] = lo;
}

// decoder weight combine: W'[768][512]
//   rows 0:256 = Wa+Wc (e1), 256:512 = Wa+Wd (e2), 512:768 = Wb (e1*e2)
__global__ void prep_decw(const float* __restrict__ w1, u16* __restrict__ Wh,
                          u16* __restrict__ Wl) {
    int t = blockIdx.x * 256 + threadIdx.x;
    if (t >= 768 * 512) return;
    int k = t >> 9, c = t & 511;
    float v;
    if (k < 256)       v = w1[(size_t)k * 512 + c] + w1[(size_t)(512 + k) * 512 + c];
    else if (k < 512)  v = w1[(size_t)(k - 256) * 512 + c] + w1[(size_t)(768 + k - 256) * 512 + c];
    else               v = w1[(size_t)(256 + k - 512) * 512 + c];
    u16 h = f2bf(v);
    u16 lo = f2bf(v - bf2f(h));
    int dst = ((k >> 3) * 512 + c) * 8 + (k & 7);
    Wh[dst] = h; Wl[dst] = lo;
}

// ---------------------------------------------------------------------------
// split-bf16 MFMA GEMM: C[128x128 per block] = A[.,256] @ W[256,nout]
// ---------------------------------------------------------------------------
template <int EPI, bool RELU>
__global__ __launch_bounds__(512) void mfma_gemm(
        const u16* __restrict__ Ah, const u16* __restrict__ Al,
        const u16* __restrict__ Bh, const u16* __restrict__ Bl,
        const float* __restrict__ bias,
        u16* __restrict__ Ch, u16* __restrict__ Cl,
        float* __restrict__ Cf, int ldc, int coloff,
        int n, int nout) {
    __shared__ __align__(16) u16 As[2][2][4][128][8];   // [buf][hl][kg][row][j]
    __shared__ __align__(16) u16 Bs[2][2][4][128][8];   // [buf][hl][kg][col][j]
    int t = threadIdx.x;
    int w = t >> 6, lm = t & 15, lg = (t >> 4) & 3;
    int row0 = blockIdx.x * 128;
    int c0   = blockIdx.y * 128;
    int srow = t & 127, skg = (t >> 7) & 3;

    int garow = min(row0 + srow, n - 1);
    const u16* gAh = Ah + (size_t)garow * 256 + skg * 8;
    const u16* gAl = Al + (size_t)garow * 256 + skg * 8;
    const u16* gBh = Bh + ((size_t)skg * nout + c0 + srow) * 8;
    const u16* gBl = Bl + ((size_t)skg * nout + c0 + srow) * 8;
    const size_t bstep = (size_t)4 * nout * 8;

    f32x4 acc[8] = {};
    uint4 rAh, rAl, rBh, rBl;

    rAh = *(const uint4*)(gAh);
    rAl = *(const uint4*)(gAl);
    rBh = *(const uint4*)(gBh);
    rBl = *(const uint4*)(gBl);
    *(uint4*)&As[0][0][skg][srow][0] = rAh;
    *(uint4*)&As[0][1][skg][srow][0] = rAl;
    *(uint4*)&Bs[0][0][skg][srow][0] = rBh;
    *(uint4*)&Bs[0][1][skg][srow][0] = rBl;
    __syncthreads();

    int cur = 0;
#pragma unroll
    for (int c = 0; c < 8; ++c) {
        if (c < 7) {   // T14: issue next-chunk loads early
            rAh = *(const uint4*)(gAh + (c + 1) * 32);
            rAl = *(const uint4*)(gAl + (c + 1) * 32);
            rBh = *(const uint4*)(gBh + (c + 1) * bstep);
            rBl = *(const uint4*)(gBl + (c + 1) * bstep);
        }
        s8v bh = *(const s8v*)&Bs[cur][0][lg][w * 16 + lm][0];
        s8v bl = *(const s8v*)&Bs[cur][1][lg][w * 16 + lm][0];
#pragma unroll
        for (int R = 0; R < 8; R += 2) {
            s8v ah0 = *(const s8v*)&As[cur][0][lg][R * 16 + lm][0];
            s8v al0 = *(const s8v*)&As[cur][1][lg][R * 16 + lm][0];
            s8v ah1 = *(const s8v*)&As[cur][0][lg][(R + 1) * 16 + lm][0];
            s8v al1 = *(const s8v*)&As[cur][1][lg][(R + 1) * 16 + lm][0];
            acc[R]     = mfma16(ah0, bh, acc[R]);
            acc[R + 1] = mfma16(ah1, bh, acc[R + 1]);
            acc[R]     = mfma16(ah0, bl, acc[R]);
            acc[R + 1] = mfma16(ah1, bl, acc[R + 1]);
            acc[R]     = mfma16(al0, bh, acc[R]);
            acc[R + 1] = mfma16(al1, bh, acc[R + 1]);
        }
        if (c < 7) {   // write-late
            int nb = cur ^ 1;
            *(uint4*)&As[nb][0][skg][srow][0] = rAh;
            *(uint4*)&As[nb][1][skg][srow][0] = rAl;
            *(uint4*)&Bs[nb][0][skg][srow][0] = rBh;
            *(uint4*)&Bs[nb][1][skg][srow][0] = rBl;
        }
        __syncthreads();
        cur ^= 1;
    }

    int cg = c0 + w * 16 + lm;
    float bv = bias[cg];
#pragma unroll
    for (int R = 0; R < 8; ++R) {
#pragma unroll
        for (int i = 0; i < 4; ++i) {
            int r = row0 + R * 16 + lg * 4 + i;
            if (r < n) {
                float v = acc[R][i] + bv;
                if (RELU) v = fmaxf(v, 0.f);
                if (EPI == 0) {
                    u16 hbv = f2bf(v);
                    Ch[(size_t)r * 256 + cg] = hbv;
                    Cl[(size_t)r * 256 + cg] = f2bf(v - bf2f(hbv));
                } else {
                    Cf[(size_t)r * ldc + coloff + cg] = v;
                }
            }
        }
    }
}

// ---------------------------------------------------------------------------
// Fused decoder v2: hidden = e1@(Wa+Wc) + e2@(Wa+Wd) + (e1*e2)@Wb  (K=768)
// ONE block per 64 pairs covers ALL 512 hidden cols (gathers each row once).
// B (weights, 1.5MB, L2-hot) read directly from global, coalesced.
// 512 threads = 8 waves; wave w owns cols [w*64, w*64+64) x all 64 pairs.
// ---------------------------------------------------------------------------
__global__ __launch_bounds__(512) void decoder_mfma(
        const float* __restrict__ x2os, const int* __restrict__ idx0,
        const int* __restrict__ idx1,
        const u16* __restrict__ Wh, const u16* __restrict__ Wl,   // [96][512][8]
        const float* __restrict__ b1, const float* __restrict__ w2,
        float* __restrict__ partial) {
    __shared__ __align__(16) u16 As[2][2][4][64][8];   // [buf][hl][kg][row][j] 16KB
    int t = threadIdx.x;
    int w = t >> 6, lm = t & 15, lg = (t >> 4) & 3;
    int p0 = blockIdx.x * 64;

    // staging role: slot = t>>1 in [0,256): (srow, skg); half = t&1 (4 elems)
    int slot = t >> 1, half = t & 1;
    int srow = slot & 63, skg = slot >> 6;
    int p = min(p0 + srow, PPAIRS - 1);
    int n1 = idx0[p], n2 = idx1[p];
    const float* e1p = x2os + (size_t)n1 * 256;
    const float* e2p = x2os + (size_t)n2 * 256;

    f32x4 acc[4][4] = {};
    f4 r1, r2;

    auto loadA = [&](int c) {
        int kb = c * 32;
        int reg = kb >> 8;                       // 0:e1  1:e2  2:e1*e2
        int fb = (kb & 255) + skg * 8 + half * 4;
        if (reg == 0)      { r1 = *(const f4*)(e1p + fb); }
        else if (reg == 1) { r1 = *(const f4*)(e2p + fb); }
        else {               r1 = *(const f4*)(e1p + fb); r2 = *(const f4*)(e2p + fb); }
    };
    auto writeA = [&](int nb, int c) {
        int reg = (c * 32) >> 8;
        f4 v = r1;
        if (reg == 2) v *= r2;
        u16 hb[4], lb[4];
#pragma unroll
        for (int q = 0; q < 4; ++q) { hb[q] = f2bf(v[q]); lb[q] = f2bf(v[q] - bf2f(hb[q])); }
        uint2 hv, lv;
        hv.x = (uint32_t)hb[0] | ((uint32_t)hb[1] << 16);
        hv.y = (uint32_t)hb[2] | ((uint32_t)hb[3] << 16);
        lv.x = (uint32_t)lb[0] | ((uint32_t)lb[1] << 16);
        lv.y = (uint32_t)lb[2] | ((uint32_t)lb[3] << 16);
        *(uint2*)&As[nb][0][skg][srow][half * 4] = hv;
        *(uint2*)&As[nb][1][skg][srow][half * 4] = lv;
    };

    loadA(0);
    writeA(0, 0);
    __syncthreads();

    int cur = 0;
#pragma unroll 1
    for (int c = 0; c < 24; ++c) {
        if (c < 23) loadA(c + 1);     // issue next gathers early (T14)
        // B fragments straight from global (k-grouped, coalesced, L2-hot)
        s8v bh[4], bl[4];
#pragma unroll
        for (int ct = 0; ct < 4; ++ct) {
            size_t boff = ((size_t)(c * 4 + lg) * 512 + w * 64 + ct * 16 + lm) * 8;
            bh[ct] = *(const s8v*)(Wh + boff);
            bl[ct] = *(const s8v*)(Wl + boff);
        }
#pragma unroll
        for (int R = 0; R < 4; ++R) {
            s8v ah = *(const s8v*)&As[cur][0][lg][R * 16 + lm][0];
            s8v al = *(const s8v*)&As[cur][1][lg][R * 16 + lm][0];
#pragma unroll
            for (int ct = 0; ct < 4; ++ct) {
                acc[R][ct] = mfma16(ah, bh[ct], acc[R][ct]);
                acc[R][ct] = mfma16(ah, bl[ct], acc[R][ct]);
                acc[R][ct] = mfma16(al, bh[ct], acc[R][ct]);
            }
        }
        if (c < 23) writeA(cur ^ 1, c + 1);   // write-late
        __syncthreads();
        cur ^= 1;
    }

    // epilogue: relu+bias, dot with w2 over this wave's 64 cols, reduce 16 lanes
    float bv[4], wv[4];
#pragma unroll
    for (int ct = 0; ct < 4; ++ct) {
        int cg = w * 64 + ct * 16 + lm;
        bv[ct] = b1[cg]; wv[ct] = w2[cg];
    }
#pragma unroll
    for (int R = 0; R < 4; ++R) {
#pragma unroll
        for (int i = 0; i < 4; ++i) {
            float v = 0.f;
#pragma unroll
            for (int ct = 0; ct < 4; ++ct)
                v += fmaxf(acc[R][ct][i] + bv[ct], 0.f) * wv[ct];
            v += __shfl_xor(v, 1);
            v += __shfl_xor(v, 2);
            v += __shfl_xor(v, 4);
            v += __shfl_xor(v, 8);
            if (lm == 0) {
                int pr = p0 + R * 16 + lg * 4 + i;
                if (pr < PPAIRS) partial[(size_t)pr * 8 + w] = v;
            }
        }
    }
}

__global__ void finalize_out(const float* __restrict__ partial,
                             const float* __restrict__ b2, float* __restrict__ out) {
    int p = blockIdx.x * 256 + threadIdx.x;
    if (p < PPAIRS) {
        float s = 0.f;
#pragma unroll
        for (int q = 0; q < 2; ++q) {
            f4 v = *(const f4*)&partial[(size_t)p * 8 + q * 4];
            s += v[0] + v[1] + v[2] + v[3];
        }
        out[p] = s + b2[0];
    }
}

// ---------------------------------------------------------------------------
// readout / discriminator (fp32, cheap)
// ---------------------------------------------------------------------------
__global__ void colsum(const float* __restrict__ x, float* __restrict__ mean_out, int n) {
    int rows = (n + gridDim.x - 1) / gridDim.x;
    int r0 = blockIdx.x * rows;
    int r1 = min(r0 + rows, n);
    float s = 0.f;
    for (int r = r0; r < r1; ++r) s += x[(size_t)r * FDIM + threadIdx.x];
    atomicAdd(&mean_out[threadIdx.x], s);
}

__global__ void disc_prep(const float* __restrict__ means, const float* __restrict__ disc_w,
                          float* __restrict__ vv, float invn) {
    __shared__ float c0[256], c1[256];
    int t = threadIdx.x;
    c0[t] = 1.f / (1.f + expf(-means[t] * invn));
    c1[t] = 1.f / (1.f + expf(-means[256 + t] * invn));
    __syncthreads();
    float v0 = 0.f, v1 = 0.f;
    for (int j = 0; j < 256; ++j) {
        float wv = disc_w[t * 256 + j];
        v0 += wv * c0[j];
        v1 += wv * c1[j];
    }
    vv[t] = v0;
    vv[256 + t] = v1;
}

__global__ __launch_bounds__(256) void disc_score(
        const float* __restrict__ x2os, const float* __restrict__ x2a,
        const float* __restrict__ vv, const float* __restrict__ disc_b,
        float* __restrict__ ret_os, float* __restrict__ ret_osa, int n) {
    int gw = (blockIdx.x * 256 + threadIdx.x) >> 6;
    int l  = threadIdx.x & 63;
    if (gw >= n) return;
    f4 a  = *(const f4*)&x2os[(size_t)gw * FDIM + 4 * l];
    f4 b  = *(const f4*)&x2a[(size_t)gw * FDIM + 4 * l];
    f4 v0 = *(const f4*)&vv[4 * l];
    f4 v1 = *(const f4*)&vv[256 + 4 * l];
    float d1 = a[0]*v0[0] + a[1]*v0[1] + a[2]*v0[2] + a[3]*v0[3];
    float d2 = b[0]*v0[0] + b[1]*v0[1] + b[2]*v0[2] + b[3]*v0[3];
    float d3 = b[0]*v1[0] + b[1]*v1[1] + b[2]*v1[2] + b[3]*v1[3];
    float d4 = a[0]*v1[0] + a[1]*v1[1] + a[2]*v1[2] + a[3]*v1[3];
    for (int off = 32; off > 0; off >>= 1) {
        d1 += __shfl_down(d1, off);
        d2 += __shfl_down(d2, off);
        d3 += __shfl_down(d3, off);
        d4 += __shfl_down(d4, off);
    }
    if (l == 0) {
        float db = disc_b[0];
        ret_os[2 * gw]      = d1 + db;
        ret_os[2 * gw + 1]  = d2 + db;
        ret_osa[2 * gw]     = d3 + db;
        ret_osa[2 * gw + 1] = d4 + db;
    }
}

// ---------------------------------------------------------------------------
extern "C" void kernel_launch(void* const* d_in, const int* in_sizes, int n_in,
                              void* d_out, int out_size, void* d_ws, size_t ws_size,
                              hipStream_t stream) {
    const float* x_o   = (const float*)d_in[0];
    const float* x_a   = (const float*)d_in[1];
    const int*   ei_o  = (const int*)d_in[2];
    const int*   ei_s  = (const int*)d_in[3];
    const int*   idx   = (const int*)d_in[4];
    const float* eps_o1 = (const float*)d_in[5];
    const float* w1_o1 = (const float*)d_in[6];
    const float* b1_o1 = (const float*)d_in[7];
    const float* w2_o1 = (const float*)d_in[8];
    const float* b2_o1 = (const float*)d_in[9];
    const float* eps_s1 = (const float*)d_in[10];
    const float* w1_s1 = (const float*)d_in[11];
    const float* b1_s1 = (const float*)d_in[12];
    const float* w2_s1 = (const float*)d_in[13];
    const float* b2_s1 = (const float*)d_in[14];
    const float* eps_o2 = (const float*)d_in[15];
    const float* w1_o2 = (const float*)d_in[16];
    const float* b1_o2 = (const float*)d_in[17];
    const float* w2_o2 = (const float*)d_in[18];
    const float* b2_o2 = (const float*)d_in[19];
    const float* eps_s2 = (const float*)d_in[20];
    const float* w1_s2 = (const float*)d_in[21];
    const float* b1_s2 = (const float*)d_in[22];
    const float* w2_s2 = (const float*)d_in[23];
    const float* b2_s2 = (const float*)d_in[24];
    const float* disc_w = (const float*)d_in[25];
    const float* disc_b = (const float*)d_in[26];
    const float* dec1_w = (const float*)d_in[27];
    const float* dec1_b = (const float*)d_in[28];
    const float* dec2_w = (const float*)d_in[29];
    const float* dec2_b = (const float*)d_in[30];

    float* out_log = (float*)d_out;
    float* ret_os  = out_log + PPAIRS;
    float* ret_osa = ret_os + 2 * N_NODES;
    float* x2_os   = ret_osa + 2 * N_NODES;

    char* wp = (char*)d_ws;
    auto alloc = [&](size_t bytes) -> void* {
        void* p = (void*)wp;
        wp += (bytes + 255) & ~(size_t)255;
        return p;
    };
    int*   rowptr_o = (int*)alloc((N_NODES + 1) * sizeof(int));
    int*   rowptr_s = (int*)alloc((N_NODES + 1) * sizeof(int));
    int*   col_o    = (int*)alloc((size_t)N_EDGES * sizeof(int));
    int*   col_s    = (int*)alloc((size_t)N_EDGES * sizeof(int));
    int*   cursor   = (int*)alloc((size_t)N_NODES * sizeof(int));
    u16*   hh       = (u16*)alloc((size_t)N_NODES * FDIM * 2);
    u16*   hl       = (u16*)alloc((size_t)N_NODES * FDIM * 2);
    u16*   th       = (u16*)alloc((size_t)N_NODES * FDIM * 2);
    u16*   tl       = (u16*)alloc((size_t)N_NODES * FDIM * 2);
    float* x1buf    = (float*)alloc((size_t)N_NODES * FDIM * sizeof(float));
    float* x2a      = (float*)alloc((size_t)N_NODES * FDIM * sizeof(float));
    float* partial  = (float*)alloc((size_t)PPAIRS * 8 * sizeof(float));
    float* means    = (float*)alloc(512 * sizeof(float));
    float* vv       = (float*)alloc(512 * sizeof(float));
    u16* w1h[4]; u16* w1l[4]; u16* w2h[4]; u16* w2l[4];
    for (int i = 0; i < 4; ++i) {
        w1h[i] = (u16*)alloc(256 * 256 * 2); w1l[i] = (u16*)alloc(256 * 256 * 2);
        w2h[i] = (u16*)alloc(256 * 128 * 2); w2l[i] = (u16*)alloc(256 * 128 * 2);
    }
    u16* decWh = (u16*)alloc(768 * 512 * 2);
    u16* decWl = (u16*)alloc(768 * 512 * 2);

    const int EB = (N_EDGES + 255) / 256;
    hipMemsetAsync(means, 0, 512 * sizeof(float), stream);

    // CSR (o)
    hipMemsetAsync(cursor, 0, N_NODES * sizeof(int), stream);
    count_deg<<<EB, 256, 0, stream>>>(ei_o + N_EDGES, cursor, N_EDGES);
    exclusive_scan<<<1, 1024, 0, stream>>>(cursor, rowptr_o, N_NODES);
    hipMemsetAsync(cursor, 0, N_NODES * sizeof(int), stream);
    fill_csr<<<EB, 256, 0, stream>>>(ei_o, ei_o + N_EDGES, rowptr_o, cursor, col_o, N_EDGES);
    // CSR (s)
    hipMemsetAsync(cursor, 0, N_NODES * sizeof(int), stream);
    count_deg<<<EB, 256, 0, stream>>>(ei_s + N_EDGES, cursor, N_EDGES);
    exclusive_scan<<<1, 1024, 0, stream>>>(cursor, rowptr_s, N_NODES);
    hipMemsetAsync(cursor, 0, N_NODES * sizeof(int), stream);
    fill_csr<<<EB, 256, 0, stream>>>(ei_s, ei_s + N_EDGES, rowptr_s, cursor, col_s, N_EDGES);

    // weight prep
    const float* w1s[4] = {w1_o1, w1_s1, w1_o2, w1_s2};
    const float* w2s[4] = {w2_o1, w2_s1, w2_o2, w2_s2};
    for (int i = 0; i < 4; ++i) {
        split_w<<<(256 * 256 + 255) / 256, 256, 0, stream>>>(w1s[i], w1h[i], w1l[i], 256, 256);
        split_w<<<(256 * 128 + 255) / 256, 256, 0, stream>>>(w2s[i], w2h[i], w2l[i], 256, 128);
    }
    prep_decw<<<(768 * 512 + 255) / 256, 256, 0, stream>>>(dec1_w, decWh, decWl);

    const int AGGB = (N_NODES + 3) / 4;
    const int RB   = (N_NODES + 127) / 128;   // 391

    auto conv = [&](const float* xin, const int* rp, const int* cl, const float* epsv,
                    int wi, const float* b1v, const float* b2v,
                    float* outbuf, int coloff, bool relu2) {
        agg_h_split<<<AGGB, 256, 0, stream>>>(xin, rp, cl, epsv, hh, hl, N_NODES);
        mfma_gemm<0, true><<<dim3(RB, 2), 512, 0, stream>>>(
            hh, hl, w1h[wi], w1l[wi], b1v, th, tl, nullptr, 0, 0, N_NODES, 256);
        if (relu2)
            mfma_gemm<1, true><<<dim3(RB, 1), 512, 0, stream>>>(
                th, tl, w2h[wi], w2l[wi], b2v, nullptr, nullptr, outbuf, 256, coloff, N_NODES, 128);
        else
            mfma_gemm<1, false><<<dim3(RB, 1), 512, 0, stream>>>(
                th, tl, w2h[wi], w2l[wi], b2v, nullptr, nullptr, outbuf, 256, coloff, N_NODES, 128);
    };

    auto encode = [&](const float* x, float* x2out) {
        conv(x,     rowptr_o, col_o, eps_o1, 0, b1_o1, b2_o1, x1buf, 0,   true);
        conv(x,     rowptr_s, col_s, eps_s1, 1, b1_s1, b2_s1, x1buf, 128, true);
        conv(x1buf, rowptr_o, col_o, eps_o2, 2, b1_o2, b2_o2, x2out, 0,   false);
        conv(x1buf, rowptr_s, col_s, eps_s2, 3, b1_s2, b2_s2, x2out, 128, false);
    };

    encode(x_o, x2_os);
    encode(x_a, x2a);

    colsum<<<128, 256, 0, stream>>>(x2_os, means, N_NODES);
    colsum<<<128, 256, 0, stream>>>(x2a, means + 256, N_NODES);
    disc_prep<<<1, 256, 0, stream>>>(means, disc_w, vv, 1.0f / (float)N_NODES);
    disc_score<<<(N_NODES + 3) / 4, 256, 0, stream>>>(x2_os, x2a, vv, disc_b,
                                                      ret_os, ret_osa, N_NODES);

    const int DB = (PPAIRS + 63) / 64;   // 1563
    decoder_mfma<<<DB, 512, 0, stream>>>(x2_os, idx, idx + PPAIRS,
                                         decWh, decWl, dec1_b, dec2_w, partial);
    finalize_out<<<(PPAIRS + 255) / 256, 256, 0, stream>>>(partial, dec2_b, out_log);
}